// Round 1
// baseline (306.927 us; speedup 1.0000x reference)
//
#include <hip/hip_runtime.h>
#include <hip/hip_bf16.h>
#include <cstdint>

#define BATCH 8
#define SEQ   4096
#define DIN   1024
#define DST   64
#define CHUNK 64
#define NC    (SEQ/CHUNK)   // 64 chunks per batch

typedef __attribute__((ext_vector_type(8))) short short8;
typedef __attribute__((ext_vector_type(4))) short short4v;
typedef __attribute__((ext_vector_type(4))) float f32x4;

__device__ __forceinline__ short f2bf(float f) {
    union { float f; unsigned u; } v; v.f = f;
    unsigned r = v.u + 0x7fffu + ((v.u >> 16) & 1u);   // RNE
    return (short)(r >> 16);
}
__device__ __forceinline__ float softplus_f(float x) {
    return (x > 20.f) ? x : log1pf(expf(x));
}

// ---------------- k0: precompute ----------------
// blocks 0..63: row n of B_bar (bf16) + reduction a[n] = mean_i exp(delta_i * A_n)
// blocks 64..79: convert C (f32 [1024][64]) -> bf16 same layout
__global__ void ssm_k0(const float* __restrict__ logA, const float* __restrict__ Bm,
                       const float* __restrict__ Cm, const float* __restrict__ logdelta,
                       short* __restrict__ Bb, short* __restrict__ Cb,
                       float* __restrict__ a_o, float* __restrict__ l2a_o,
                       float* __restrict__ aL_o)
{
    __shared__ float red[256];
    int blk = blockIdx.x, tid = threadIdx.x;
    if (blk < DST) {
        int n = blk;
        float An = -expf(logA[n]);
        float acc = 0.f;
        #pragma unroll
        for (int ii = 0; ii < DIN/256; ++ii) {
            int i = ii*256 + tid;
            float dlt = softplus_f(logdelta[i]);
            Bb[n*DIN + i] = f2bf(Bm[n*DIN + i] * dlt);
            acc += expf(dlt * An);
        }
        red[tid] = acc; __syncthreads();
        for (int s = 128; s > 0; s >>= 1) {
            if (tid < s) red[tid] += red[tid + s];
            __syncthreads();
        }
        if (tid == 0) {
            float a = red[0] * (1.f/DIN);
            a_o[n]   = a;
            l2a_o[n] = log2f(a);
            float p = a;
            #pragma unroll
            for (int q = 0; q < 6; ++q) p = p*p;      // a^64 = a^CHUNK
            aL_o[n] = p;
        }
    } else {
        int base = (blk - DST) * (DIN*DST/16);
        for (int e = tid; e < DIN*DST/16; e += 256)
            Cb[base + e] = f2bf(Cm[base + e]);
    }
}

// ---------------- k1: Bu GEMM (MFMA) + chunk-local scan ----------------
// block = one (batch, chunk of 64 t). 4 waves, each a 16-row m-tile, N=64 via 4 n-tiles.
__global__ __launch_bounds__(256) void ssm_k1(
    const float* __restrict__ u, const short* __restrict__ Bb,
    const float* __restrict__ a_i, float* __restrict__ xloc, float* __restrict__ carry)
{
    int blk = blockIdx.x;                 // b*NC + c
    int b = blk >> 6, c = blk & (NC-1);
    int tid = threadIdx.x;
    int w = tid >> 6, lane = tid & 63;
    int m = lane & 15, quad = lane >> 4;

    long row = ((long)b << 12) + (c << 6) + (w << 4) + m;   // global bt row
    const float* up = u + row * DIN + quad * 8;

    f32x4 acc0 = {0,0,0,0}, acc1 = {0,0,0,0}, acc2 = {0,0,0,0}, acc3 = {0,0,0,0};

    #pragma unroll 4
    for (int ks = 0; ks < DIN/32; ++ks) {
        const float4* uv = (const float4*)(up + ks*32);
        float4 ua = uv[0];
        float4 ub = uv[1];
        short8 af;
        af[0]=f2bf(ua.x); af[1]=f2bf(ua.y); af[2]=f2bf(ua.z); af[3]=f2bf(ua.w);
        af[4]=f2bf(ub.x); af[5]=f2bf(ub.y); af[6]=f2bf(ub.z); af[7]=f2bf(ub.w);
        const short* bbase = Bb + ks*32 + quad*8;
        short8 b0 = *(const short8*)(bbase + ( 0 + m)*DIN);
        short8 b1 = *(const short8*)(bbase + (16 + m)*DIN);
        short8 b2 = *(const short8*)(bbase + (32 + m)*DIN);
        short8 b3 = *(const short8*)(bbase + (48 + m)*DIN);
        acc0 = __builtin_amdgcn_mfma_f32_16x16x32_bf16(af, b0, acc0, 0,0,0);
        acc1 = __builtin_amdgcn_mfma_f32_16x16x32_bf16(af, b1, acc1, 0,0,0);
        acc2 = __builtin_amdgcn_mfma_f32_16x16x32_bf16(af, b2, acc2, 0,0,0);
        acc3 = __builtin_amdgcn_mfma_f32_16x16x32_bf16(af, b3, acc3, 0,0,0);
    }

    __shared__ float bu[CHUNK][DST];
    int trow = (w << 4) + (quad << 2);
    #pragma unroll
    for (int r = 0; r < 4; ++r) {
        bu[trow + r][ 0 + m] = acc0[r];
        bu[trow + r][16 + m] = acc1[r];
        bu[trow + r][32 + m] = acc2[r];
        bu[trow + r][48 + m] = acc3[r];
    }
    __syncthreads();

    if (tid < DST) {                       // wave 0 does the 64-step local scan
        int n = tid;
        float an = a_i[n];
        float x = 0.f;
        float* xp = xloc + (((long)b << 12) + (c << 6)) * DST + n;
        #pragma unroll 8
        for (int t = 0; t < CHUNK; ++t) {
            x = x * an + bu[t][n];
            xp[(long)t * DST] = x;
        }
        carry[(b * NC + c) * DST + n] = x;
    }
}

// ---------------- k2: cross-chunk carry prefix ----------------
__global__ void ssm_k2(const float* __restrict__ carry, const float* __restrict__ aL,
                       float* __restrict__ Xin)
{
    int b = blockIdx.x, n = threadIdx.x;
    float x = 0.f, al = aL[n];
    for (int c = 0; c < NC; ++c) {
        Xin[(b*NC + c)*DST + n] = x;                  // state entering chunk c
        x = x * al + carry[(b*NC + c)*DST + n];
    }
}

// ---------------- k3: y = C@x_true + D*u (MFMA, K=64) ----------------
// block = 16 t-rows x full I=1024. Corrected x staged to LDS as bf16 once.
__global__ __launch_bounds__(256) void ssm_k3(
    const float* __restrict__ u, const float* __restrict__ xloc,
    const float* __restrict__ Xin, const float* __restrict__ l2a,
    const short* __restrict__ Cb, const float* __restrict__ D,
    float* __restrict__ y)
{
    int tblk = blockIdx.x;                 // 2048 blocks
    long t0 = (long)tblk << 4;
    int b = (int)(t0 >> 12);
    int tloc0 = (int)(t0 & (SEQ-1));
    int chunk = tloc0 >> 6;                // 16-row tile never crosses a 64-chunk
    int jbase = tloc0 & (CHUNK-1);

    __shared__ short xb[16][DST];          // bf16 corrected x, 128B rows

    int tid = threadIdx.x;
    {
        int m  = tid >> 4;
        int n0 = (tid & 15) * 4;
        long t = t0 + m;
        int j  = jbase + m;
        float4 xv = *(const float4*)(xloc + t*DST + n0);
        float4 xi = *(const float4*)(Xin + (long)(b*NC + chunk)*DST + n0);
        float4 la = *(const float4*)(l2a + n0);
        float jp = (float)(j + 1);
        short4v xs;
        xs[0] = f2bf(xv.x + exp2f(jp*la.x)*xi.x);
        xs[1] = f2bf(xv.y + exp2f(jp*la.y)*xi.y);
        xs[2] = f2bf(xv.z + exp2f(jp*la.z)*xi.z);
        xs[3] = f2bf(xv.w + exp2f(jp*la.w)*xi.w);
        *(short4v*)(&xb[m][n0]) = xs;
    }
    __syncthreads();

    int w = tid >> 6, lane = tid & 63;
    int n16 = lane & 15, quad = lane >> 4;

    // A-fragments (x rows) — shared by every i-tile of this wave
    short8 a0 = *(const short8*)(&xb[n16][ 0 + quad*8]);
    short8 a1 = *(const short8*)(&xb[n16][32 + quad*8]);

    #pragma unroll 4
    for (int ii = 0; ii < 16; ++ii) {
        int i0 = (ii*4 + w) * 16;
        int i  = i0 + n16;
        const short* cb = Cb + (long)i*DST + quad*8;
        short8 b0 = *(const short8*)(cb);
        short8 b1 = *(const short8*)(cb + 32);
        f32x4 acc = {0,0,0,0};
        acc = __builtin_amdgcn_mfma_f32_16x16x32_bf16(a0, b0, acc, 0,0,0);
        acc = __builtin_amdgcn_mfma_f32_16x16x32_bf16(a1, b1, acc, 0,0,0);
        float Di = D[i];
        #pragma unroll
        for (int r = 0; r < 4; ++r) {
            long t = t0 + quad*4 + r;
            long off = t*DIN + i;
            y[off] = acc[r] + Di * u[off];
        }
    }
}

extern "C" void kernel_launch(void* const* d_in, const int* in_sizes, int n_in,
                              void* d_out, int out_size, void* d_ws, size_t ws_size,
                              hipStream_t stream)
{
    const float* u        = (const float*)d_in[0];
    const float* logA     = (const float*)d_in[1];
    const float* Bm       = (const float*)d_in[2];
    const float* Cm       = (const float*)d_in[3];
    const float* D        = (const float*)d_in[4];
    const float* logdelta = (const float*)d_in[5];
    float* y = (float*)d_out;

    char* ws = (char*)d_ws;
    float* xloc  = (float*)(ws);                             // 8 MiB
    float* carry = (float*)(ws + 8u*1024*1024);              // 128 KiB
    float* Xin   = (float*)(ws + 8u*1024*1024 + 128*1024);   // 128 KiB
    short* Bb    = (short*)(ws + 8u*1024*1024 + 256*1024);   // 128 KiB bf16 B_bar
    short* Cb    = (short*)(ws + 8u*1024*1024 + 384*1024);   // 128 KiB bf16 C
    float* a_o   = (float*)(ws + 8u*1024*1024 + 512*1024);
    float* l2a_o = a_o + 64;
    float* aL_o  = a_o + 128;

    hipLaunchKernelGGL(ssm_k0, dim3(DST + 16), dim3(256), 0, stream,
                       logA, Bm, Cm, logdelta, Bb, Cb, a_o, l2a_o, aL_o);
    hipLaunchKernelGGL(ssm_k1, dim3(BATCH*NC), dim3(256), 0, stream,
                       u, Bb, a_o, xloc, carry);
    hipLaunchKernelGGL(ssm_k2, dim3(BATCH), dim3(DST), 0, stream,
                       carry, aL_o, Xin);
    hipLaunchKernelGGL(ssm_k3, dim3((BATCH*SEQ)/16), dim3(256), 0, stream,
                       u, xloc, Xin, l2a_o, Cb, D, y);
}